// Round 5
// baseline (452.367 us; speedup 1.0000x reference)
//
#include <hip/hip_runtime.h>
#include <math.h>

// Problem constants
#define Bn  2
#define Sn  2048
#define Hn  2048
#define NHn 16
#define HDn 128
#define Mn  (Bn * Sn)   // 4096
#define Kd  Hn          // 2048

typedef __attribute__((ext_vector_type(8))) short bf16x8;   // 8 bf16 in 4 VGPRs
typedef __attribute__((ext_vector_type(4))) float fx4;

__device__ __forceinline__ unsigned short f2bf(float f) {
    union { float f; unsigned u; } v; v.f = f;
    unsigned r = v.u + 0x7fffu + ((v.u >> 16) & 1u);   // RNE (finite inputs)
    return (unsigned short)(r >> 16);
}

// async global->LDS, 16B per lane; LDS dest = wave-uniform base + lane*16
__device__ __forceinline__ void gload16(const unsigned short* g, unsigned short* l) {
    __builtin_amdgcn_global_load_lds(
        (const __attribute__((address_space(1))) unsigned int*)g,
        (__attribute__((address_space(3))) unsigned int*)l, 16, 0, 0);
}

__device__ __forceinline__ fx4 mfma16(bf16x8 a, bf16x8 b, fx4 c) {
    return __builtin_amdgcn_mfma_f32_16x16x32_bf16(a, b, c, 0, 0, 0);
}

// ---------------- fp32 -> bf16 cast kernels ----------------
__global__ __launch_bounds__(256)
void cvt_kernel(const float* __restrict__ src, unsigned short* __restrict__ dst, int n8)
{
    int i = blockIdx.x * 256 + threadIdx.x;
    if (i >= n8) return;
    const float4* s = (const float4*)src + (size_t)i * 2;
    float4 a = s[0], b = s[1];
    bf16x8 o;
    o[0] = (short)f2bf(a.x); o[1] = (short)f2bf(a.y);
    o[2] = (short)f2bf(a.z); o[3] = (short)f2bf(a.w);
    o[4] = (short)f2bf(b.x); o[5] = (short)f2bf(b.y);
    o[6] = (short)f2bf(b.z); o[7] = (short)f2bf(b.w);
    *(bf16x8*)(dst + (size_t)i * 8) = o;
}

__global__ __launch_bounds__(256)
void cvt4_kernel(const float* __restrict__ w0, const float* __restrict__ w1,
                 const float* __restrict__ w2, const float* __restrict__ w3,
                 unsigned short* __restrict__ d0, unsigned short* __restrict__ d1,
                 unsigned short* __restrict__ d2, unsigned short* __restrict__ d3,
                 int n8)
{
    int i = blockIdx.x * 256 + threadIdx.x;
    if (i >= n8) return;
    const float* w = (blockIdx.y == 0) ? w0 : (blockIdx.y == 1) ? w1
                    : (blockIdx.y == 2) ? w2 : w3;
    unsigned short* d = (blockIdx.y == 0) ? d0 : (blockIdx.y == 1) ? d1
                       : (blockIdx.y == 2) ? d2 : d3;
    const float4* s = (const float4*)w + (size_t)i * 2;
    float4 a = s[0], b = s[1];
    bf16x8 o;
    o[0] = (short)f2bf(a.x); o[1] = (short)f2bf(a.y);
    o[2] = (short)f2bf(a.z); o[3] = (short)f2bf(a.w);
    o[4] = (short)f2bf(b.x); o[5] = (short)f2bf(b.y);
    o[6] = (short)f2bf(b.z); o[7] = (short)f2bf(b.w);
    *(bf16x8*)(d + (size_t)i * 8) = o;
}

// ---------------- 256x256 deep-pipelined MFMA GEMM core ----------------
// C = A (MxK) * W^T (W is NxK), bf16. BK=64, 8 waves (2Mx4N), per-wave 128x64.
// LDS 128 KB: A/B x 2 dbuf x 2 halves x [128][64] bf16, XOR-swizzled
// (c ^= ((r>>2)&3)<<4, applied on global SOURCE for linear DMA dest and on
// ds_read addresses -> bank-uniform frag reads). 4 quadrant-phases per K-tile;
// single vmcnt(0) drain per tile at Q3 (stages issued at Q0/Q1, ~3 phases early).
#define HALF_SH 8192          // shorts per [128][64] half
#define B_BASE  32768         // B region offset in shorts

__device__ __forceinline__ void gemm256(const unsigned short* __restrict__ A,
                                        const unsigned short* __restrict__ W,
                                        int m0, int n0, fx4 acc[8][4],
                                        unsigned short* smem)
{
    const int t = threadIdx.x;
    const int wid = t >> 6, lane = t & 63;
    const int wm = wid >> 2, wn = wid & 3;
    const int lr = lane & 15, lg = lane >> 4;
    const int swr = ((lr >> 2) & 3) << 4;    // read-side swizzle (row bits 2-3)

    // staging geometry: flat = t + q*512 ; row = flat>>3 ; c8 = (flat&7)*8
    const int row0 = t >> 3,         row1 = (t + 512) >> 3;
    const int gc0 = ((t & 7) * 8) ^ (((row0 >> 2) & 3) << 4);
    const int gc1 = ((t & 7) * 8) ^ (((row1 >> 2) & 3) << 4);
    const unsigned short* Ag[2][2];   // [half][q]
    const unsigned short* Bg[2][2];
    Ag[0][0] = A + (size_t)(m0 + row0) * Kd + gc0;
    Ag[0][1] = A + (size_t)(m0 + row1) * Kd + gc1;
    Ag[1][0] = A + (size_t)(m0 + 128 + row0) * Kd + gc0;
    Ag[1][1] = A + (size_t)(m0 + 128 + row1) * Kd + gc1;
    Bg[0][0] = W + (size_t)(n0 + row0) * Kd + gc0;
    Bg[0][1] = W + (size_t)(n0 + row1) * Kd + gc1;
    Bg[1][0] = W + (size_t)(n0 + 128 + row0) * Kd + gc0;
    Bg[1][1] = W + (size_t)(n0 + 128 + row1) * Kd + gc1;
    const int dst0 = wid * 512;              // (wid*64)*8 shorts
    const int dst1 = wid * 512 + 4096;       // (+512 lanes)*8

    bf16x8 aM[4][2], bLo[2][2], bHi[2][2];

    auto STAGE_A = [&](int buf, int koff) {
        gload16(Ag[0][0] + koff, smem + (buf * 2 + 0) * HALF_SH + dst0);
        gload16(Ag[0][1] + koff, smem + (buf * 2 + 0) * HALF_SH + dst1);
        gload16(Ag[1][0] + koff, smem + (buf * 2 + 1) * HALF_SH + dst0);
        gload16(Ag[1][1] + koff, smem + (buf * 2 + 1) * HALF_SH + dst1);
    };
    auto STAGE_B = [&](int buf, int koff) {
        gload16(Bg[0][0] + koff, smem + B_BASE + (buf * 2 + 0) * HALF_SH + dst0);
        gload16(Bg[0][1] + koff, smem + B_BASE + (buf * 2 + 0) * HALF_SH + dst1);
        gload16(Bg[1][0] + koff, smem + B_BASE + (buf * 2 + 1) * HALF_SH + dst0);
        gload16(Bg[1][1] + koff, smem + B_BASE + (buf * 2 + 1) * HALF_SH + dst1);
    };
    auto LDA = [&](int buf, int milo) {
        const unsigned short* base = smem + (buf * 2 + wm) * HALF_SH;
        #pragma unroll
        for (int i = 0; i < 4; ++i) {
            int rl = (milo + i) * 16 + lr;
            #pragma unroll
            for (int kk = 0; kk < 2; ++kk)
                aM[i][kk] = *(const bf16x8*)(base + rl * 64 + ((kk * 32 + lg * 8) ^ swr));
        }
    };
    auto LDB = [&](int buf, int njlo, bf16x8 (&br)[2][2]) {
        const unsigned short* base = smem + B_BASE + (buf * 2 + (wn >> 1)) * HALF_SH;
        #pragma unroll
        for (int j = 0; j < 2; ++j) {
            int rl = (wn & 1) * 64 + (njlo + j) * 16 + lr;
            #pragma unroll
            for (int kk = 0; kk < 2; ++kk)
                br[j][kk] = *(const bf16x8*)(base + rl * 64 + ((kk * 32 + lg * 8) ^ swr));
        }
    };
    auto MM = [&](int milo, int njlo, bf16x8 (&br)[2][2]) {
        __builtin_amdgcn_s_setprio(1);
        #pragma unroll
        for (int i = 0; i < 4; ++i)
            #pragma unroll
            for (int j = 0; j < 2; ++j)
                #pragma unroll
                for (int kk = 0; kk < 2; ++kk)
                    acc[milo + i][njlo + j] =
                        mfma16(aM[i][kk], br[j][kk], acc[milo + i][njlo + j]);
        __builtin_amdgcn_s_setprio(0);
    };

    // prologue: stage tile 0, full drain
    STAGE_A(0, 0);
    STAGE_B(0, 0);
    asm volatile("s_waitcnt vmcnt(0)" ::: "memory");
    __builtin_amdgcn_s_barrier();

    const int NT = Kd / 64;
    for (int tk = 0; tk < NT; ++tk) {
        const int cur = tk & 1, nxt = cur ^ 1;
        const int koff = (tk + 1) * 64;
        // Q0: Mlo x Nlo (stage next A)
        if (tk + 1 < NT) STAGE_A(nxt, koff);
        LDA(cur, 0);
        LDB(cur, 0, bLo);
        __builtin_amdgcn_s_barrier();
        MM(0, 0, bLo);
        __builtin_amdgcn_s_barrier();
        // Q1: Mlo x Nhi (stage next B)
        if (tk + 1 < NT) STAGE_B(nxt, koff);
        LDB(cur, 2, bHi);
        __builtin_amdgcn_s_barrier();
        MM(0, 2, bHi);
        __builtin_amdgcn_s_barrier();
        // Q2: Mhi x Nhi
        LDA(cur, 4);
        __builtin_amdgcn_s_barrier();
        MM(4, 2, bHi);
        __builtin_amdgcn_s_barrier();
        // Q3: Mhi x Nlo (registers only) + tile-boundary drain
        MM(4, 0, bLo);
        asm volatile("s_waitcnt vmcnt(0)" ::: "memory");
        __builtin_amdgcn_s_barrier();
    }
}

// ---------------- QKV projection + RoPE (256x256 core) ----------------
__global__ __launch_bounds__(512, 2)
void qkv_kernel(const unsigned short* __restrict__ xb,
                const unsigned short* __restrict__ wq, const unsigned short* __restrict__ wk,
                const unsigned short* __restrict__ wv,
                const float* __restrict__ fcos, const float* __restrict__ fsin,
                unsigned short* __restrict__ qb, unsigned short* __restrict__ kb,
                unsigned short* __restrict__ vtb)
{
    extern __shared__ unsigned short smem[];
    const int mode = blockIdx.z;
    const unsigned short* W = (mode == 0) ? wq : (mode == 1) ? wk : wv;
    const int m0 = blockIdx.x * 256, n0 = blockIdx.y * 256;

    fx4 zero = {0.f, 0.f, 0.f, 0.f};
    fx4 acc[8][4];
    #pragma unroll
    for (int i = 0; i < 8; ++i)
        #pragma unroll
        for (int j = 0; j < 4; ++j) acc[i][j] = zero;

    gemm256(xb, W, m0, n0, acc, smem);

    const int t = threadIdx.x, wid = t >> 6, lane = t & 63;
    const int wm = wid >> 2, wn = wid & 3, lr = lane & 15, lg = lane >> 4;
    if (mode < 2) {
        unsigned short* outp = (mode == 0) ? qb : kb;
        #pragma unroll
        for (int mi = 0; mi < 8; ++mi) {
            int mbase = m0 + wm * 128 + mi * 16 + lg * 4;
            #pragma unroll
            for (int nj = 0; nj < 4; ++nj) {
                int ncol = n0 + wn * 64 + nj * 16 + lr;
                int h = ncol >> 7, dh = ncol & 127;   // head, d-within-head
                #pragma unroll
                for (int r = 0; r < 4; ++r) {
                    int m = mbase + r, b = m >> 11, s = m & (Sn - 1);
                    float vv = acc[mi][nj][r];
                    float other = __shfl_xor(vv, 1, 64);   // partner holds d^1
                    float c  = fcos[s * (HDn / 2) + (dh >> 1)];
                    float sn = fsin[s * (HDn / 2) + (dh >> 1)];
                    float res = (dh & 1) ? (other * sn + vv * c) : (vv * c - other * sn);
                    outp[(((size_t)b * NHn + h) * Sn + s) * HDn + dh] = f2bf(res);
                }
            }
        }
    } else {
        #pragma unroll
        for (int mi = 0; mi < 8; ++mi) {
            int mbase = m0 + wm * 128 + mi * 16 + lg * 4;
            int b = mbase >> 11, s = mbase & (Sn - 1);    // 4 rows stay in one b
            #pragma unroll
            for (int nj = 0; nj < 4; ++nj) {
                int ncol = n0 + wn * 64 + nj * 16 + lr;
                int h = ncol >> 7, dh = ncol & 127;
                ushort4 pk;
                pk.x = f2bf(acc[mi][nj][0]); pk.y = f2bf(acc[mi][nj][1]);
                pk.z = f2bf(acc[mi][nj][2]); pk.w = f2bf(acc[mi][nj][3]);
                *(ushort4*)(vtb + (((size_t)b * NHn + h) * HDn + dh) * Sn + s) = pk;
            }
        }
    }
}

// ---------------- Output projection (fp32 out, 256x256 core) ----------------
__global__ __launch_bounds__(512, 2)
void oproj_kernel(const unsigned short* __restrict__ attnb,
                  const unsigned short* __restrict__ wob, float* __restrict__ out)
{
    extern __shared__ unsigned short smem[];
    const int m0 = blockIdx.x * 256, n0 = blockIdx.y * 256;
    fx4 zero = {0.f, 0.f, 0.f, 0.f};
    fx4 acc[8][4];
    #pragma unroll
    for (int i = 0; i < 8; ++i)
        #pragma unroll
        for (int j = 0; j < 4; ++j) acc[i][j] = zero;

    gemm256(attnb, wob, m0, n0, acc, smem);

    const int t = threadIdx.x, wid = t >> 6, lane = t & 63;
    const int wm = wid >> 2, wn = wid & 3, lr = lane & 15, lg = lane >> 4;
    #pragma unroll
    for (int mi = 0; mi < 8; ++mi) {
        #pragma unroll
        for (int r = 0; r < 4; ++r) {
            int m = m0 + wm * 128 + mi * 16 + lg * 4 + r;
            #pragma unroll
            for (int nj = 0; nj < 4; ++nj)
                out[(size_t)m * Hn + n0 + wn * 64 + nj * 16 + lr] = acc[mi][nj][r];
        }
    }
}

// ---------------- Flash attention (unchanged from round 4) ----------------
#define KROW 136   // shorts per K-tile row
#define VROW 72    // shorts per Vt-tile row
#define PROW 68    // shorts per P row

__global__ __launch_bounds__(256)
void attn_kernel(const unsigned short* __restrict__ qb,
                 const unsigned short* __restrict__ kb,
                 const unsigned short* __restrict__ vtb,
                 const int* __restrict__ pmask, unsigned short* __restrict__ attnb)
{
    __shared__ unsigned short Ksl[64 * KROW];
    __shared__ unsigned short Vsl[128 * VROW];
    __shared__ unsigned short Psl[4 * 16 * PROW];

    const int pr = blockIdx.x, h = blockIdx.y, b = blockIdx.z;
    const size_t base = ((size_t)b * NHn + h) * Sn * HDn;
    const unsigned short* Qp = qb + base;
    const unsigned short* Kp = kb + base;
    const unsigned short* Vt = vtb + base;      // (d, s)
    const int t = threadIdx.x, w = t >> 6, lane = t & 63;
    const int lr = lane & 15, lg = lane >> 4;
    const float scale = 0.08838834764831845f;   // 1/sqrt(128)
    fx4 zero = {0.f, 0.f, 0.f, 0.f};

    for (int ph = 0; ph < 2; ++ph) {
        const int qt = ph ? (31 - pr) : pr;
        const int q0 = qt * 64;
        const int nt = qt + 1;

        bf16x8 qf[4];
        #pragma unroll
        for (int kf = 0; kf < 4; ++kf)
            qf[kf] = *(const bf16x8*)(Qp + (size_t)(q0 + w * 16 + lr) * HDn + kf * 32 + lg * 8);

        fx4 oacc[8];
        #pragma unroll
        for (int j = 0; j < 8; ++j) oacc[j] = zero;
        float mrow[4] = {-1e30f, -1e30f, -1e30f, -1e30f};
        float lsum[4] = {0.f, 0.f, 0.f, 0.f};

        bf16x8 kreg[4], vreg[4];
        #pragma unroll
        for (int q = 0; q < 4; ++q) {
            int chunk = t + q * 256, row = chunk >> 4, c = chunk & 15;
            kreg[q] = *(const bf16x8*)(Kp + (size_t)row * HDn + c * 8);
        }
        #pragma unroll
        for (int q = 0; q < 4; ++q) {
            int chunk = t + q * 256, row = chunk >> 3, c = chunk & 7;
            vreg[q] = *(const bf16x8*)(Vt + (size_t)row * Sn + c * 8);
        }

        for (int kt = 0; kt < nt; ++kt) {
            const int kv0 = kt * 64;
            __syncthreads();
            #pragma unroll
            for (int q = 0; q < 4; ++q) {
                int chunk = t + q * 256, row = chunk >> 4, c = chunk & 15;
                *(bf16x8*)(Ksl + row * KROW + c * 8) = kreg[q];
            }
            #pragma unroll
            for (int q = 0; q < 4; ++q) {
                int chunk = t + q * 256, row = chunk >> 3, c = chunk & 7;
                *(bf16x8*)(Vsl + row * VROW + c * 8) = vreg[q];
            }
            __syncthreads();
            if (kt + 1 < nt) {
                #pragma unroll
                for (int q = 0; q < 4; ++q) {
                    int chunk = t + q * 256, row = chunk >> 4, c = chunk & 15;
                    kreg[q] = *(const bf16x8*)(Kp + (size_t)(kv0 + 64 + row) * HDn + c * 8);
                }
                #pragma unroll
                for (int q = 0; q < 4; ++q) {
                    int chunk = t + q * 256, row = chunk >> 3, c = chunk & 7;
                    vreg[q] = *(const bf16x8*)(Vt + (size_t)row * Sn + kv0 + 64 + c * 8);
                }
            }

            fx4 sc[4];
            __builtin_amdgcn_s_setprio(1);
            #pragma unroll
            for (int nf = 0; nf < 4; ++nf) {
                fx4 z = zero;
                #pragma unroll
                for (int kf = 0; kf < 4; ++kf) {
                    bf16x8 kfr = *(const bf16x8*)(Ksl + (nf * 16 + lr) * KROW + kf * 32 + lg * 8);
                    z = __builtin_amdgcn_mfma_f32_16x16x32_bf16(qf[kf], kfr, z, 0, 0, 0);
                }
                sc[nf] = z;
            }
            __builtin_amdgcn_s_setprio(0);

            float pmv[4];
            #pragma unroll
            for (int nf = 0; nf < 4; ++nf)
                pmv[nf] = pmask[b * Sn + kv0 + nf * 16 + lr] ? 0.f : -10000.f;
            float tmax[4];
            #pragma unroll
            for (int r = 0; r < 4; ++r) {
                int qrow = q0 + w * 16 + lg * 4 + r;
                float mx = -1e30f;
                #pragma unroll
                for (int nf = 0; nf < 4; ++nf) {
                    int kg = kv0 + nf * 16 + lr;
                    float v = sc[nf][r] * scale + pmv[nf] + ((kg > qrow) ? -1e9f : 0.f);
                    sc[nf][r] = v;
                    mx = fmaxf(mx, v);
                }
                tmax[r] = mx;
            }
            #pragma unroll
            for (int off = 1; off < 16; off <<= 1)
                #pragma unroll
                for (int r = 0; r < 4; ++r)
                    tmax[r] = fmaxf(tmax[r], __shfl_xor(tmax[r], off, 64));
            float grow = 0.f;
            #pragma unroll
            for (int r = 0; r < 4; ++r) grow = fmaxf(grow, tmax[r] - mrow[r]);
            if (__any(grow > 8.f)) {
                #pragma unroll
                for (int r = 0; r < 4; ++r) {
                    float mnew = fmaxf(mrow[r], tmax[r]);
                    float sf = __expf(mrow[r] - mnew);
                    mrow[r] = mnew;
                    lsum[r] *= sf;
                    #pragma unroll
                    for (int j = 0; j < 8; ++j) oacc[j][r] *= sf;
                }
            }
            float psum[4];
            #pragma unroll
            for (int r = 0; r < 4; ++r) {
                float ps = 0.f;
                #pragma unroll
                for (int nf = 0; nf < 4; ++nf) {
                    float p = __expf(sc[nf][r] - mrow[r]);
                    sc[nf][r] = p;
                    ps += p;
                }
                psum[r] = ps;
            }
            #pragma unroll
            for (int off = 1; off < 16; off <<= 1)
                #pragma unroll
                for (int r = 0; r < 4; ++r)
                    psum[r] += __shfl_xor(psum[r], off, 64);
            #pragma unroll
            for (int r = 0; r < 4; ++r) lsum[r] += psum[r];

            unsigned short* Pw = Psl + w * 16 * PROW;
            #pragma unroll
            for (int nf = 0; nf < 4; ++nf)
                #pragma unroll
                for (int r = 0; r < 4; ++r)
                    Pw[(lg * 4 + r) * PROW + nf * 16 + lr] = f2bf(sc[nf][r]);
            __builtin_amdgcn_s_setprio(1);
            #pragma unroll
            for (int kf2 = 0; kf2 < 2; ++kf2) {
                bf16x8 pf = *(const bf16x8*)(Pw + lr * PROW + kf2 * 32 + lg * 8);
                #pragma unroll
                for (int j = 0; j < 8; ++j) {
                    bf16x8 vf = *(const bf16x8*)(Vsl + (j * 16 + lr) * VROW + kf2 * 32 + lg * 8);
                    oacc[j] = __builtin_amdgcn_mfma_f32_16x16x32_bf16(pf, vf, oacc[j], 0, 0, 0);
                }
            }
            __builtin_amdgcn_s_setprio(0);
        }

        #pragma unroll
        for (int j = 0; j < 8; ++j) {
            int d = j * 16 + lr;
            #pragma unroll
            for (int r = 0; r < 4; ++r) {
                int s = q0 + w * 16 + lg * 4 + r;
                attnb[((size_t)b * Sn + s) * Hn + h * HDn + d] = f2bf(oacc[j][r] / lsum[r]);
            }
        }
        __syncthreads();
    }
}

// ---------------- launch ----------------
extern "C" void kernel_launch(void* const* d_in, const int* in_sizes, int n_in,
                              void* d_out, int out_size, void* d_ws, size_t ws_size,
                              hipStream_t stream)
{
    const float* x     = (const float*)d_in[0];
    const float* fcos  = (const float*)d_in[1];
    const float* fsin  = (const float*)d_in[2];
    const int*   pmask = (const int*)d_in[3];
    const float* Wq    = (const float*)d_in[4];
    const float* Wk    = (const float*)d_in[5];
    const float* Wv    = (const float*)d_in[6];
    const float* Wo    = (const float*)d_in[7];
    float* out = (float*)d_out;
    (void)in_sizes; (void)n_in; (void)out_size; (void)ws_size;

    const size_t NX = (size_t)Mn * Hn;        // 8,388,608
    const size_t NW = (size_t)Hn * Hn;        // 4,194,304
    unsigned short* xb   = (unsigned short*)d_ws;
    unsigned short* wqb  = xb  + NX;
    unsigned short* wkb  = wqb + NW;
    unsigned short* wvb  = wkb + NW;
    unsigned short* wob  = wvb + NW;
    unsigned short* qb   = wob + NW;
    unsigned short* kb   = qb  + NX;
    unsigned short* vtb  = kb  + NX;
    unsigned short* attnb= vtb + NX;          // total ~117 MB

    const int GEMM_LDS = 131072;              // 128 KB dynamic LDS
    hipFuncSetAttribute((const void*)qkv_kernel,
                        hipFuncAttributeMaxDynamicSharedMemorySize, GEMM_LDS);
    hipFuncSetAttribute((const void*)oproj_kernel,
                        hipFuncAttributeMaxDynamicSharedMemorySize, GEMM_LDS);

    cvt_kernel<<<dim3((int)(NX / 8 / 256)), 256, 0, stream>>>(x, xb, (int)(NX / 8));
    cvt4_kernel<<<dim3((int)(NW / 8 / 256), 4), 256, 0, stream>>>(
        Wq, Wk, Wv, Wo, wqb, wkb, wvb, wob, (int)(NW / 8));
    qkv_kernel<<<dim3(Mn / 256, Hn / 256, 3), 512, GEMM_LDS, stream>>>(
        xb, wqb, wkb, wvb, fcos, fsin, qb, kb, vtb);
    attn_kernel<<<dim3(16, NHn, Bn), 256, 0, stream>>>(qb, kb, vtb, pmask, attnb);
    oproj_kernel<<<dim3(Mn / 256, Hn / 256), 512, GEMM_LDS, stream>>>(attnb, wob, out);
}

// Round 6
// 422.199 us; speedup vs baseline: 1.0715x; 1.0715x over previous
//
#include <hip/hip_runtime.h>
#include <math.h>

// Problem constants
#define Bn  2
#define Sn  2048
#define Hn  2048
#define NHn 16
#define HDn 128
#define Mn  (Bn * Sn)   // 4096
#define Kd  Hn          // 2048

typedef __attribute__((ext_vector_type(8))) short bf16x8;   // 8 bf16 in 4 VGPRs
typedef __attribute__((ext_vector_type(4))) float fx4;

__device__ __forceinline__ unsigned short f2bf(float f) {
    union { float f; unsigned u; } v; v.f = f;
    unsigned r = v.u + 0x7fffu + ((v.u >> 16) & 1u);   // RNE (finite inputs)
    return (unsigned short)(r >> 16);
}

// async global->LDS, 16B per lane; LDS dest = wave-uniform base + lane*16
__device__ __forceinline__ void gload16(const unsigned short* g, unsigned short* l) {
    __builtin_amdgcn_global_load_lds(
        (const __attribute__((address_space(1))) unsigned int*)g,
        (__attribute__((address_space(3))) unsigned int*)l, 16, 0, 0);
}

__device__ __forceinline__ fx4 mfma16(bf16x8 a, bf16x8 b, fx4 c) {
    return __builtin_amdgcn_mfma_f32_16x16x32_bf16(a, b, c, 0, 0, 0);
}

// ---------------- fp32 -> bf16 cast kernels ----------------
__global__ __launch_bounds__(256)
void cvt_kernel(const float* __restrict__ src, unsigned short* __restrict__ dst, int n8)
{
    int i = blockIdx.x * 256 + threadIdx.x;
    if (i >= n8) return;
    const float4* s = (const float4*)src + (size_t)i * 2;
    float4 a = s[0], b = s[1];
    bf16x8 o;
    o[0] = (short)f2bf(a.x); o[1] = (short)f2bf(a.y);
    o[2] = (short)f2bf(a.z); o[3] = (short)f2bf(a.w);
    o[4] = (short)f2bf(b.x); o[5] = (short)f2bf(b.y);
    o[6] = (short)f2bf(b.z); o[7] = (short)f2bf(b.w);
    *(bf16x8*)(dst + (size_t)i * 8) = o;
}

__global__ __launch_bounds__(256)
void cvt4_kernel(const float* __restrict__ w0, const float* __restrict__ w1,
                 const float* __restrict__ w2, const float* __restrict__ w3,
                 unsigned short* __restrict__ d0, unsigned short* __restrict__ d1,
                 unsigned short* __restrict__ d2, unsigned short* __restrict__ d3,
                 int n8)
{
    int i = blockIdx.x * 256 + threadIdx.x;
    if (i >= n8) return;
    const float* w = (blockIdx.y == 0) ? w0 : (blockIdx.y == 1) ? w1
                    : (blockIdx.y == 2) ? w2 : w3;
    unsigned short* d = (blockIdx.y == 0) ? d0 : (blockIdx.y == 1) ? d1
                       : (blockIdx.y == 2) ? d2 : d3;
    const float4* s = (const float4*)w + (size_t)i * 2;
    float4 a = s[0], b = s[1];
    bf16x8 o;
    o[0] = (short)f2bf(a.x); o[1] = (short)f2bf(a.y);
    o[2] = (short)f2bf(a.z); o[3] = (short)f2bf(a.w);
    o[4] = (short)f2bf(b.x); o[5] = (short)f2bf(b.y);
    o[6] = (short)f2bf(b.z); o[7] = (short)f2bf(b.w);
    *(bf16x8*)(d + (size_t)i * 8) = o;
}

// ---------------- 256x256 counted-vmcnt MFMA GEMM core ----------------
// C = A (MxK) * W^T (W is NxK), bf16. BK=64, 8 waves (2Mx4N), per-wave 128x64.
// LDS 128 KB = 2 dbuf x {A,B} x 2 halves x [128][64] bf16.
// 3-bit XOR slot swizzle: 16B-slot ^= (row>>1)&7, applied on the global SOURCE
// (linear DMA dest) and mirrored on ds_read -> <=2-way bank aliasing (free).
// Load units (per tile, issue order): A.g0 x2 (rows 0-63 of each half, Q0),
// B x4 (Q1), A.g1 x2 (rows 64-127, Q2). Counted waits: vmcnt(2) at tile end
// (early-6 of next tile retired, late-2 fly), vmcnt(6) before Q2's LDA
// (previous late-2 retired). Never vmcnt(0) in steady state.
#define HALF_SH 8192          // shorts per [128][64] half
#define B_BASE  32768         // B region offset in shorts

__device__ __forceinline__ void gemm256(const unsigned short* __restrict__ A,
                                        const unsigned short* __restrict__ W,
                                        int m0, int n0, fx4 acc[8][4],
                                        unsigned short* smem)
{
    const int t = threadIdx.x;
    const int wid = t >> 6, lane = t & 63;
    const int wm = wid >> 2, wn = wid & 3;
    const int lr = lane & 15, lg = lane >> 4;
    const int swr = ((lr >> 1) & 7) << 3;    // read-side slot swizzle (shorts)

    // staging geometry: row0 = t>>3 in 0..63 (g0), row0+64 (g1); col slot (t&7)
    // pre-swizzled on the global source by F(row) = ((row>>1)&7) (row-bit 1..3,
    // identical for g0/g1 rows and matching read rows mod 16).
    const int row0 = t >> 3;
    const int gcs  = ((t & 7) * 8) ^ (((t >> 4) & 7) << 3);
    const unsigned short* Ag[2][2];   // [half][g]
    const unsigned short* Bg[2][2];
    Ag[0][0] = A + (size_t)(m0 + row0) * Kd + gcs;
    Ag[0][1] = A + (size_t)(m0 + row0 + 64) * Kd + gcs;
    Ag[1][0] = A + (size_t)(m0 + 128 + row0) * Kd + gcs;
    Ag[1][1] = A + (size_t)(m0 + 128 + row0 + 64) * Kd + gcs;
    Bg[0][0] = W + (size_t)(n0 + row0) * Kd + gcs;
    Bg[0][1] = W + (size_t)(n0 + row0 + 64) * Kd + gcs;
    Bg[1][0] = W + (size_t)(n0 + 128 + row0) * Kd + gcs;
    Bg[1][1] = W + (size_t)(n0 + 128 + row0 + 64) * Kd + gcs;
    const int dst0 = wid * 512;              // rows 0..63 region
    const int dst1 = wid * 512 + 4096;       // rows 64..127 region

    bf16x8 aM[4][2], bLo[2][2], bHi[2][2];

    auto ISSUE_A_EARLY = [&](int buf, int koff) {
        gload16(Ag[0][0] + koff, smem + (buf * 2 + 0) * HALF_SH + dst0);
        gload16(Ag[1][0] + koff, smem + (buf * 2 + 1) * HALF_SH + dst0);
    };
    auto ISSUE_B = [&](int buf, int koff) {
        gload16(Bg[0][0] + koff, smem + B_BASE + (buf * 2 + 0) * HALF_SH + dst0);
        gload16(Bg[0][1] + koff, smem + B_BASE + (buf * 2 + 0) * HALF_SH + dst1);
        gload16(Bg[1][0] + koff, smem + B_BASE + (buf * 2 + 1) * HALF_SH + dst0);
        gload16(Bg[1][1] + koff, smem + B_BASE + (buf * 2 + 1) * HALF_SH + dst1);
    };
    auto ISSUE_A_LATE = [&](int buf, int koff) {
        gload16(Ag[0][1] + koff, smem + (buf * 2 + 0) * HALF_SH + dst1);
        gload16(Ag[1][1] + koff, smem + (buf * 2 + 1) * HALF_SH + dst1);
    };
    auto LDA = [&](int buf, int milo) {
        const unsigned short* base = smem + (buf * 2 + wm) * HALF_SH;
        #pragma unroll
        for (int i = 0; i < 4; ++i) {
            int rl = (milo + i) * 16 + lr;
            #pragma unroll
            for (int kk = 0; kk < 2; ++kk)
                aM[i][kk] = *(const bf16x8*)(base + rl * 64 + ((kk * 32 + lg * 8) ^ swr));
        }
    };
    auto LDB = [&](int buf, int njlo, bf16x8 (&br)[2][2]) {
        const unsigned short* base = smem + B_BASE + (buf * 2 + (wn >> 1)) * HALF_SH;
        #pragma unroll
        for (int j = 0; j < 2; ++j) {
            int rl = (wn & 1) * 64 + (njlo + j) * 16 + lr;
            #pragma unroll
            for (int kk = 0; kk < 2; ++kk)
                br[j][kk] = *(const bf16x8*)(base + rl * 64 + ((kk * 32 + lg * 8) ^ swr));
        }
    };
    auto MM = [&](int milo, int njlo, bf16x8 (&br)[2][2]) {
        __builtin_amdgcn_s_setprio(1);
        #pragma unroll
        for (int i = 0; i < 4; ++i)
            #pragma unroll
            for (int j = 0; j < 2; ++j)
                #pragma unroll
                for (int kk = 0; kk < 2; ++kk)
                    acc[milo + i][njlo + j] =
                        mfma16(aM[i][kk], br[j][kk], acc[milo + i][njlo + j]);
        __builtin_amdgcn_s_setprio(0);
    };

    // prologue: issue tile 0 in consumption order; retire early-6, late-2 fly
    ISSUE_A_EARLY(0, 0);
    ISSUE_B(0, 0);
    ISSUE_A_LATE(0, 0);
    asm volatile("s_waitcnt vmcnt(2)" ::: "memory");
    __builtin_amdgcn_s_barrier();

    const int NT = Kd / 64;
    for (int tk = 0; tk < NT; ++tk) {
        const int cur = tk & 1, nxt = cur ^ 1;
        const int koff = (tk + 1) * 64;
        const bool more = (tk + 1 < NT);
        // Q0: Mlo x Nlo   (issue next early-A)
        if (more) ISSUE_A_EARLY(nxt, koff);
        LDA(cur, 0);
        LDB(cur, 0, bLo);
        __builtin_amdgcn_s_barrier();
        MM(0, 0, bLo);
        __builtin_amdgcn_s_barrier();
        // Q1: Mlo x Nhi   (issue next B)
        if (more) ISSUE_B(nxt, koff);
        LDB(cur, 2, bHi);
        __builtin_amdgcn_s_barrier();
        MM(0, 2, bHi);
        // retire this tile's late-2 (A.g1) before Q2 reads them; keep next-6 in flight
        if (more) { asm volatile("s_waitcnt vmcnt(6)" ::: "memory"); }
        else      { asm volatile("s_waitcnt vmcnt(0)" ::: "memory"); }
        __builtin_amdgcn_s_barrier();
        // Q2: Mhi x Nhi   (issue next late-A)
        if (more) ISSUE_A_LATE(nxt, koff);
        LDA(cur, 4);
        __builtin_amdgcn_s_barrier();
        MM(4, 2, bHi);
        __builtin_amdgcn_s_barrier();
        // Q3: Mhi x Nlo (register-only) + retire next tile's early-6
        MM(4, 0, bLo);
        asm volatile("s_waitcnt vmcnt(2)" ::: "memory");
        __builtin_amdgcn_s_barrier();
    }
}

// ---------------- QKV projection + RoPE (256x256 core) ----------------
// Q is pre-scaled by 1/sqrt(HD) here (saves a mul per score element in attn).
__global__ __launch_bounds__(512, 2)
void qkv_kernel(const unsigned short* __restrict__ xb,
                const unsigned short* __restrict__ wq, const unsigned short* __restrict__ wk,
                const unsigned short* __restrict__ wv,
                const float* __restrict__ fcos, const float* __restrict__ fsin,
                unsigned short* __restrict__ qb, unsigned short* __restrict__ kb,
                unsigned short* __restrict__ vtb)
{
    extern __shared__ unsigned short smem[];
    const int mode = blockIdx.z;
    const unsigned short* W = (mode == 0) ? wq : (mode == 1) ? wk : wv;
    const int m0 = blockIdx.x * 256, n0 = blockIdx.y * 256;

    fx4 zero = {0.f, 0.f, 0.f, 0.f};
    fx4 acc[8][4];
    #pragma unroll
    for (int i = 0; i < 8; ++i)
        #pragma unroll
        for (int j = 0; j < 4; ++j) acc[i][j] = zero;

    gemm256(xb, W, m0, n0, acc, smem);

    const int t = threadIdx.x, wid = t >> 6, lane = t & 63;
    const int wm = wid >> 2, wn = wid & 3, lr = lane & 15, lg = lane >> 4;
    if (mode < 2) {
        unsigned short* outp = (mode == 0) ? qb : kb;
        const float qsc = (mode == 0) ? 0.08838834764831845f : 1.0f;
        #pragma unroll
        for (int mi = 0; mi < 8; ++mi) {
            int mbase = m0 + wm * 128 + mi * 16 + lg * 4;
            #pragma unroll
            for (int nj = 0; nj < 4; ++nj) {
                int ncol = n0 + wn * 64 + nj * 16 + lr;
                int h = ncol >> 7, dh = ncol & 127;   // head, d-within-head
                #pragma unroll
                for (int r = 0; r < 4; ++r) {
                    int m = mbase + r, b = m >> 11, s = m & (Sn - 1);
                    float vv = acc[mi][nj][r];
                    float other = __shfl_xor(vv, 1, 64);   // partner holds d^1
                    float c  = fcos[s * (HDn / 2) + (dh >> 1)];
                    float sn = fsin[s * (HDn / 2) + (dh >> 1)];
                    float res = (dh & 1) ? (other * sn + vv * c) : (vv * c - other * sn);
                    outp[(((size_t)b * NHn + h) * Sn + s) * HDn + dh] = f2bf(res * qsc);
                }
            }
        }
    } else {
        #pragma unroll
        for (int mi = 0; mi < 8; ++mi) {
            int mbase = m0 + wm * 128 + mi * 16 + lg * 4;
            int b = mbase >> 11, s = mbase & (Sn - 1);    // 4 rows stay in one b
            #pragma unroll
            for (int nj = 0; nj < 4; ++nj) {
                int ncol = n0 + wn * 64 + nj * 16 + lr;
                int h = ncol >> 7, dh = ncol & 127;
                ushort4 pk;
                pk.x = f2bf(acc[mi][nj][0]); pk.y = f2bf(acc[mi][nj][1]);
                pk.z = f2bf(acc[mi][nj][2]); pk.w = f2bf(acc[mi][nj][3]);
                *(ushort4*)(vtb + (((size_t)b * NHn + h) * HDn + dh) * Sn + s) = pk;
            }
        }
    }
}

// ---------------- m97 128x128 GEMM core (for oproj: grid 512 blocks, 2/CU) ----
__device__ __forceinline__ void gemm_mfma(const unsigned short* __restrict__ A,
                                          const unsigned short* __restrict__ W,
                                          int m0, int n0, fx4 acc[4][4],
                                          unsigned short* Asl, unsigned short* Bsl)
{
    const int t = threadIdx.x;
    const int w = t >> 6, lane = t & 63;
    const int wm = w >> 1, wn = w & 1;
    const int lr = lane & 15, lg = lane >> 4;

    const int srow = w * 32 + (lane >> 2);
    const int scol = (lane & 3) * 8;
    const unsigned short* Ag0 = A + (size_t)(m0 + srow) * Kd + scol;
    const unsigned short* Ag1 = Ag0 + (size_t)16 * Kd;
    const unsigned short* Bg0 = W + (size_t)(n0 + srow) * Kd + scol;
    const unsigned short* Bg1 = Bg0 + (size_t)16 * Kd;
    unsigned short* Ad0 = Asl + w * 1024;
    unsigned short* Ad1 = Asl + w * 1024 + 512;
    unsigned short* Bd0 = Bsl + w * 1024;
    unsigned short* Bd1 = Bsl + w * 1024 + 512;

    for (int k0 = 0; k0 < Kd; k0 += 32) {
        __syncthreads();
        gload16(Ag0 + k0, Ad0);
        gload16(Ag1 + k0, Ad1);
        gload16(Bg0 + k0, Bd0);
        gload16(Bg1 + k0, Bd1);
        __syncthreads();

        bf16x8 af[4], bfr[4];
        #pragma unroll
        for (int i = 0; i < 4; ++i)
            af[i] = *(const bf16x8*)(Asl + (wm * 64 + i * 16 + lr) * 32 + lg * 8);
        #pragma unroll
        for (int j = 0; j < 4; ++j)
            bfr[j] = *(const bf16x8*)(Bsl + (wn * 64 + j * 16 + lr) * 32 + lg * 8);
        #pragma unroll
        for (int i = 0; i < 4; ++i)
            #pragma unroll
            for (int j = 0; j < 4; ++j)
                acc[i][j] = mfma16(af[i], bfr[j], acc[i][j]);
    }
}

__global__ __launch_bounds__(256)
void oproj_kernel(const unsigned short* __restrict__ attnb,
                  const unsigned short* __restrict__ wob, float* __restrict__ out)
{
    __shared__ unsigned short Asl[128 * 32];
    __shared__ unsigned short Bsl[128 * 32];
    const int m0 = blockIdx.x * 128, n0 = blockIdx.y * 128;
    fx4 zero = {0.f, 0.f, 0.f, 0.f};
    fx4 acc[4][4];
    #pragma unroll
    for (int i = 0; i < 4; ++i)
        #pragma unroll
        for (int j = 0; j < 4; ++j) acc[i][j] = zero;

    gemm_mfma(attnb, wob, m0, n0, acc, Asl, Bsl);

    const int t = threadIdx.x, w = t >> 6, lane = t & 63;
    const int wm = w >> 1, wn = w & 1, lr = lane & 15, lg = lane >> 4;
    #pragma unroll
    for (int i = 0; i < 4; ++i) {
        #pragma unroll
        for (int r = 0; r < 4; ++r) {
            int m = m0 + wm * 64 + i * 16 + lg * 4 + r;
            #pragma unroll
            for (int j = 0; j < 4; ++j)
                out[(size_t)m * Hn + n0 + wn * 64 + j * 16 + lr] = acc[i][j][r];
        }
    }
}

// ---------------- Flash attention, bf16 MFMA + lazy online softmax ----------------
// 4 waves x 16 q-rows; BKV=64; paired q-tiles (qt, 31-qt) -> uniform 33 tiles/block.
// Softmax-lite: Q pre-scaled; causal mask only on diagonal tile; per-lane max with
// __any ballot (cross-lane reduce/rescale only when max grows >8, T13); lsum kept
// per-lane, reduced once at the end.
#define KROW 136   // shorts per K-tile row
#define VROW 72    // shorts per Vt-tile row
#define PROW 68    // shorts per P row

__global__ __launch_bounds__(256)
void attn_kernel(const unsigned short* __restrict__ qb,
                 const unsigned short* __restrict__ kb,
                 const unsigned short* __restrict__ vtb,
                 const int* __restrict__ pmask, unsigned short* __restrict__ attnb)
{
    __shared__ unsigned short Ksl[64 * KROW];
    __shared__ unsigned short Vsl[128 * VROW];
    __shared__ unsigned short Psl[4 * 16 * PROW];

    const int pr = blockIdx.x, h = blockIdx.y, b = blockIdx.z;
    const size_t base = ((size_t)b * NHn + h) * Sn * HDn;
    const unsigned short* Qp = qb + base;
    const unsigned short* Kp = kb + base;
    const unsigned short* Vt = vtb + base;      // (d, s)
    const int t = threadIdx.x, w = t >> 6, lane = t & 63;
    const int lr = lane & 15, lg = lane >> 4;
    fx4 zero = {0.f, 0.f, 0.f, 0.f};

    for (int ph = 0; ph < 2; ++ph) {
        const int qt = ph ? (31 - pr) : pr;
        const int q0 = qt * 64;
        const int nt = qt + 1;

        bf16x8 qf[4];
        #pragma unroll
        for (int kf = 0; kf < 4; ++kf)
            qf[kf] = *(const bf16x8*)(Qp + (size_t)(q0 + w * 16 + lr) * HDn + kf * 32 + lg * 8);

        fx4 oacc[8];
        #pragma unroll
        for (int j = 0; j < 8; ++j) oacc[j] = zero;
        float mrow[4] = {-1e30f, -1e30f, -1e30f, -1e30f};
        float lsum[4] = {0.f, 0.f, 0.f, 0.f};   // per-lane partial

        bf16x8 kreg[4], vreg[4];
        #pragma unroll
        for (int q = 0; q < 4; ++q) {
            int chunk = t + q * 256, row = chunk >> 4, c = chunk & 15;
            kreg[q] = *(const bf16x8*)(Kp + (size_t)row * HDn + c * 8);
        }
        #pragma unroll
        for (int q = 0; q < 4; ++q) {
            int chunk = t + q * 256, row = chunk >> 3, c = chunk & 7;
            vreg[q] = *(const bf16x8*)(Vt + (size_t)row * Sn + c * 8);
        }

        for (int kt = 0; kt < nt; ++kt) {
            const int kv0 = kt * 64;
            __syncthreads();
            #pragma unroll
            for (int q = 0; q < 4; ++q) {
                int chunk = t + q * 256, row = chunk >> 4, c = chunk & 15;
                *(bf16x8*)(Ksl + row * KROW + c * 8) = kreg[q];
            }
            #pragma unroll
            for (int q = 0; q < 4; ++q) {
                int chunk = t + q * 256, row = chunk >> 3, c = chunk & 7;
                *(bf16x8*)(Vsl + row * VROW + c * 8) = vreg[q];
            }
            __syncthreads();
            if (kt + 1 < nt) {
                #pragma unroll
                for (int q = 0; q < 4; ++q) {
                    int chunk = t + q * 256, row = chunk >> 4, c = chunk & 15;
                    kreg[q] = *(const bf16x8*)(Kp + (size_t)(kv0 + 64 + row) * HDn + c * 8);
                }
                #pragma unroll
                for (int q = 0; q < 4; ++q) {
                    int chunk = t + q * 256, row = chunk >> 3, c = chunk & 7;
                    vreg[q] = *(const bf16x8*)(Vt + (size_t)row * Sn + kv0 + 64 + c * 8);
                }
            }

            fx4 sc[4];
            __builtin_amdgcn_s_setprio(1);
            #pragma unroll
            for (int nf = 0; nf < 4; ++nf) {
                fx4 z = zero;
                #pragma unroll
                for (int kf = 0; kf < 4; ++kf) {
                    bf16x8 kfr = *(const bf16x8*)(Ksl + (nf * 16 + lr) * KROW + kf * 32 + lg * 8);
                    z = __builtin_amdgcn_mfma_f32_16x16x32_bf16(qf[kf], kfr, z, 0, 0, 0);
                }
                sc[nf] = z;
            }
            __builtin_amdgcn_s_setprio(0);

            // mask (diag tile only) + padding, per-lane max
            float pmv[4];
            #pragma unroll
            for (int nf = 0; nf < 4; ++nf)
                pmv[nf] = pmask[b * Sn + kv0 + nf * 16 + lr] ? 0.f : -10000.f;
            const bool diag = (kt == qt);
            float tmax[4];
            #pragma unroll
            for (int r = 0; r < 4; ++r) {
                int qrow = q0 + w * 16 + lg * 4 + r;
                float mx = -1e30f;
                #pragma unroll
                for (int nf = 0; nf < 4; ++nf) {
                    float v = sc[nf][r] + pmv[nf];
                    if (diag && (kv0 + nf * 16 + lr > qrow)) v = -1e9f;
                    sc[nf][r] = v;
                    mx = fmaxf(mx, v);
                }
                tmax[r] = mx;
            }
            // lazy rescale: only when some lane's max grew past mrow + 8
            bool need = false;
            #pragma unroll
            for (int r = 0; r < 4; ++r) need = need || (tmax[r] > mrow[r] + 8.f);
            if (__any(need)) {
                #pragma unroll
                for (int off = 1; off < 16; off <<= 1)
                    #pragma unroll
                    for (int r = 0; r < 4; ++r)
                        tmax[r] = fmaxf(tmax[r], __shfl_xor(tmax[r], off, 64));
                #pragma unroll
                for (int r = 0; r < 4; ++r) {
                    float mnew = fmaxf(mrow[r], tmax[r]);
                    float sf = __expf(mrow[r] - mnew);
                    mrow[r] = mnew;
                    lsum[r] *= sf;
                    #pragma unroll
                    for (int j = 0; j < 8; ++j) oacc[j][r] *= sf;
                }
            }
            #pragma unroll
            for (int r = 0; r < 4; ++r) {
                float ps = 0.f;
                #pragma unroll
                for (int nf = 0; nf < 4; ++nf) {
                    float p = __expf(sc[nf][r] - mrow[r]);   // bounded by e^8
                    sc[nf][r] = p;
                    ps += p;
                }
                lsum[r] += ps;   // per-lane partial, no per-tile reduce
            }

            unsigned short* Pw = Psl + w * 16 * PROW;
            #pragma unroll
            for (int nf = 0; nf < 4; ++nf)
                #pragma unroll
                for (int r = 0; r < 4; ++r)
                    Pw[(lg * 4 + r) * PROW + nf * 16 + lr] = f2bf(sc[nf][r]);
            __builtin_amdgcn_s_setprio(1);
            #pragma unroll
            for (int kf2 = 0; kf2 < 2; ++kf2) {
                bf16x8 pf = *(const bf16x8*)(Pw + lr * PROW + kf2 * 32 + lg * 8);
                #pragma unroll
                for (int j = 0; j < 8; ++j) {
                    bf16x8 vf = *(const bf16x8*)(Vsl + (j * 16 + lr) * VROW + kf2 * 32 + lg * 8);
                    oacc[j] = __builtin_amdgcn_mfma_f32_16x16x32_bf16(pf, vf, oacc[j], 0, 0, 0);
                }
            }
            __builtin_amdgcn_s_setprio(0);
        }

        // final lsum reduce across the 16 lanes sharing each row
        #pragma unroll
        for (int off = 1; off < 16; off <<= 1)
            #pragma unroll
            for (int r = 0; r < 4; ++r)
                lsum[r] += __shfl_xor(lsum[r], off, 64);

        #pragma unroll
        for (int j = 0; j < 8; ++j) {
            int d = j * 16 + lr;
            #pragma unroll
            for (int r = 0; r < 4; ++r) {
                int s = q0 + w * 16 + lg * 4 + r;
                attnb[((size_t)b * Sn + s) * Hn + h * HDn + d] = f2bf(oacc[j][r] / lsum[r]);
            }
        }
        __syncthreads();   // protect Ksl/Vsl before next phase restages
    }
}

// ---------------- launch ----------------
extern "C" void kernel_launch(void* const* d_in, const int* in_sizes, int n_in,
                              void* d_out, int out_size, void* d_ws, size_t ws_size,
                              hipStream_t stream)
{
    const float* x     = (const float*)d_in[0];
    const float* fcos  = (const float*)d_in[1];
    const float* fsin  = (const float*)d_in[2];
    const int*   pmask = (const int*)d_in[3];
    const float* Wq    = (const float*)d_in[4];
    const float* Wk    = (const float*)d_in[5];
    const float* Wv    = (const float*)d_in[6];
    const float* Wo    = (const float*)d_in[7];
    float* out = (float*)d_out;
    (void)in_sizes; (void)n_in; (void)out_size; (void)ws_size;

    const size_t NX = (size_t)Mn * Hn;        // 8,388,608
    const size_t NW = (size_t)Hn * Hn;        // 4,194,304
    unsigned short* xb   = (unsigned short*)d_ws;
    unsigned short* wqb  = xb  + NX;
    unsigned short* wkb  = wqb + NW;
    unsigned short* wvb  = wkb + NW;
    unsigned short* wob  = wvb + NW;
    unsigned short* qb   = wob + NW;
    unsigned short* kb   = qb  + NX;
    unsigned short* vtb  = kb  + NX;
    unsigned short* attnb= vtb + NX;          // total ~117 MB

    const int GEMM_LDS = 131072;              // 128 KB dynamic LDS (qkv only)
    hipFuncSetAttribute((const void*)qkv_kernel,
                        hipFuncAttributeMaxDynamicSharedMemorySize, GEMM_LDS);

    cvt_kernel<<<dim3((int)(NX / 8 / 256)), 256, 0, stream>>>(x, xb, (int)(NX / 8));
    cvt4_kernel<<<dim3((int)(NW / 8 / 256), 4), 256, 0, stream>>>(
        Wq, Wk, Wv, Wo, wqb, wkb, wvb, wob, (int)(NW / 8));
    qkv_kernel<<<dim3(Mn / 256, Hn / 256, 3), 512, GEMM_LDS, stream>>>(
        xb, wqb, wkb, wvb, fcos, fsin, qb, kb, vtb);
    attn_kernel<<<dim3(16, NHn, Bn), 256, 0, stream>>>(qb, kb, vtb, pmask, attnb);
    oproj_kernel<<<dim3(Mn / 128, Hn / 128), 256, 0, stream>>>(attnb, wob, out);
}